// Round 3
// baseline (22321.556 us; speedup 1.0000x reference)
//
#include <hip/hip_runtime.h>

// R3: plain launch + manual two-level grid barrier (coop API failed R1+R2 with
// zero output => launch-time rejection). 256 blocks x 256 thr, lb(256,2) so
// >=2 blocks/CU capacity guarantees co-residency. Folded recurrence:
// gates = b + x.Wih^T + s.Wc^T,  Wc = Whh.Whr (prologue, f32->bf16),
// out(t) = s(t).Whr^T computed one step behind by blocks blk<16 (Whr in LDS).
constexpr int kB = 64, kT = 512, kD = 256, kH = 512, kG = 2048;
constexpr int kNB = 256, kNT = 256;

typedef __attribute__((ext_vector_type(8))) short bf16x8;
typedef __attribute__((ext_vector_type(4))) float f32x4;
union FU { bf16x8 v; ushort u[8]; };

__device__ __forceinline__ ushort f2bf(float x) {
    union { float f; unsigned u; } v; v.f = x;
    unsigned r = v.u + 0x7FFFu + ((v.u >> 16) & 1u);
    return (ushort)(r >> 16);
}
__device__ __forceinline__ float sigm(float x) { return 1.f / (1.f + __expf(-x)); }

__global__ void bar_init_kernel(unsigned* bar) {
    if (threadIdx.x < 32) bar[threadIdx.x] = 0u;
}

// bar[0..15]=group counters, bar[16]=root counter, bar[31]=generation
__device__ __forceinline__ void grid_barrier(unsigned* bar, int bid) {
    __syncthreads();
    if (threadIdx.x == 0) {
        __threadfence();
        unsigned gen = __hip_atomic_load(bar + 31, __ATOMIC_RELAXED, __HIP_MEMORY_SCOPE_AGENT);
        const int grp = bid >> 4;
        bool done = false;
        unsigned a = __hip_atomic_fetch_add(bar + grp, 1u, __ATOMIC_ACQ_REL, __HIP_MEMORY_SCOPE_AGENT);
        if (a == 15u) {
            unsigned r = __hip_atomic_fetch_add(bar + 16, 1u, __ATOMIC_ACQ_REL, __HIP_MEMORY_SCOPE_AGENT);
            if (r == 15u) {
                #pragma unroll
                for (int g = 0; g < 16; ++g)
                    __hip_atomic_store(bar + g, 0u, __ATOMIC_RELAXED, __HIP_MEMORY_SCOPE_AGENT);
                __hip_atomic_store(bar + 16, 0u, __ATOMIC_RELAXED, __HIP_MEMORY_SCOPE_AGENT);
                __hip_atomic_store(bar + 31, gen + 1u, __ATOMIC_RELEASE, __HIP_MEMORY_SCOPE_AGENT);
                done = true;
            }
        }
        if (!done)
            while (__hip_atomic_load(bar + 31, __ATOMIC_ACQUIRE, __HIP_MEMORY_SCOPE_AGENT) == gen)
                __builtin_amdgcn_s_sleep(1);
        __threadfence();
    }
    __syncthreads();
}

#define LOADX_FRAGS(tt)                                                        \
    {                                                                          \
        _Pragma("unroll")                                                      \
        for (int ks = 0; ks < 8; ks++) {                                       \
            const float4* xp = (const float4*)(x + ((size_t)mrow * kT + (tt)) * kD + ks * 32 + kq * 8); \
            float4 a0 = xp[0], a1 = xp[1];                                     \
            FU f;                                                              \
            f.u[0] = f2bf(a0.x); f.u[1] = f2bf(a0.y);                          \
            f.u[2] = f2bf(a0.z); f.u[3] = f2bf(a0.w);                          \
            f.u[4] = f2bf(a1.x); f.u[5] = f2bf(a1.y);                          \
            f.u[6] = f2bf(a1.z); f.u[7] = f2bf(a1.w);                          \
            axp[ks] = f.v;                                                     \
        }                                                                      \
    }

__global__ void __launch_bounds__(kNT, 2) lstm2_kernel(
    const float* __restrict__ x1, const float* __restrict__ x2,
    const float* __restrict__ wih1, const float* __restrict__ whh1,
    const float* __restrict__ b1,   const float* __restrict__ whr1,
    const float* __restrict__ wih2, const float* __restrict__ whh2,
    const float* __restrict__ b2,   const float* __restrict__ whr2,
    float* __restrict__ out, ushort* __restrict__ ws)
{
    const int bid = blockIdx.x, tid = threadIdx.x;
    const int l = bid >> 7, blk = bid & 127;

    const float* x   = l ? x2 : x1;
    const float* wih = l ? wih2 : wih1;
    const float* whh = l ? whh2 : whh1;
    const float* bb  = l ? b2 : b1;
    const float* whr = l ? whr2 : whr1;
    float* outp = out + (l ? (size_t)0 : (size_t)kB * kT * kD);

    unsigned* bar = (unsigned*)ws;                    // 128 B
    ushort* wcB = ws + 128;                           // 2 x [2048][512] bf16 (4 MB)
    ushort* wc  = wcB + (size_t)l * kG * kH;
    ushort* sB  = wcB + (size_t)2 * kG * kH;          // 2 LSTM x 2 parity x [64][512] bf16

    __shared__ ushort bpL[8192];                      // 16 KB Whr frags (proj blocks only)
    __shared__ float lgs[16][66];
    __shared__ ushort ssl[256];

    // ---------------- P0: Wc = Whh @ Whr  (f32 accum -> bf16) ----------------
    {
        const int jt = tid >> 4;
        const int j  = blk * 16 + jt;                 // Wc row (gate col) 0..2047
        const int k0 = (tid & 15) * 32;               // 32 k-columns per thread
        const float* whh_r = whh + (size_t)j * kD;
        float acc[32];
        #pragma unroll
        for (int i = 0; i < 32; i++) acc[i] = 0.f;
        for (int p = 0; p < kD; p++) {
            float w = whh_r[p];
            const float4* wr = (const float4*)(whr + (size_t)p * kH + k0);
            #pragma unroll
            for (int q = 0; q < 8; q++) {
                float4 v = wr[q];
                acc[q*4+0] = fmaf(w, v.x, acc[q*4+0]);
                acc[q*4+1] = fmaf(w, v.y, acc[q*4+1]);
                acc[q*4+2] = fmaf(w, v.z, acc[q*4+2]);
                acc[q*4+3] = fmaf(w, v.w, acc[q*4+3]);
            }
        }
        ushort* dh = wc + (size_t)j * kH + k0;
        #pragma unroll
        for (int i = 0; i < 32; i++) dh[i] = f2bf(acc[i]);
    }
    // zero the 4 s-buffers: 65536 uints, exactly one per thread
    ((unsigned*)sB)[bid * kNT + tid] = 0u;
    grid_barrier(bar, bid);

    // ---------------- persistent fragments -----------------------------------
    const int lane = tid & 63, wv = tid >> 6;
    const int n = lane & 15, kq = lane >> 4;
    const int q = n >> 2, jj = n & 3;
    const int gcol = q * kH + blk * 4 + jj;           // gate column
    const float bias = bb[gcol];
    const int mrow = wv * 16 + n;                     // A-frag batch row
    const int crow = tid & 63, cjj = tid >> 6;        // cell mapping

    bf16x8 bxh[8];                                    // Wih frags (K=256)
    #pragma unroll
    for (int ks = 0; ks < 8; ks++) {
        const float4* p = (const float4*)(wih + (size_t)gcol * kD + ks * 32 + kq * 8);
        float4 a0 = p[0], a1 = p[1];
        FU h;
        h.u[0] = f2bf(a0.x); h.u[1] = f2bf(a0.y);
        h.u[2] = f2bf(a0.z); h.u[3] = f2bf(a0.w);
        h.u[4] = f2bf(a1.x); h.u[5] = f2bf(a1.y);
        h.u[6] = f2bf(a1.z); h.u[7] = f2bf(a1.w);
        bxh[ks] = h.v;
    }
    bf16x8 bsh[16];                                   // Wc frags (K=512)
    #pragma unroll
    for (int ks = 0; ks < 16; ks++)
        bsh[ks] = *(const bf16x8*)(wc + (size_t)gcol * kH + ks * 32 + kq * 8);

    if (blk < 16 && tid < 64) {                       // stage Whr frags in LDS
        const int pn = tid & 15, pq = tid >> 4;
        const int pcol = blk * 16 + pn;
        #pragma unroll
        for (int ks = 0; ks < 16; ks++) {
            const float4* p = (const float4*)(whr + (size_t)pcol * kH + ks * 32 + pq * 8);
            float4 a0 = p[0], a1 = p[1];
            FU h;
            h.u[0] = f2bf(a0.x); h.u[1] = f2bf(a0.y);
            h.u[2] = f2bf(a0.z); h.u[3] = f2bf(a0.w);
            h.u[4] = f2bf(a1.x); h.u[5] = f2bf(a1.y);
            h.u[6] = f2bf(a1.z); h.u[7] = f2bf(a1.w);
            int addr = ((((pn * 16 + ks) * 4 + pq) * 16)) ^ ((pn & 7) << 4);
            *(bf16x8*)((char*)bpL + addr) = h.v;
        }
    }

    bf16x8 axp[8];
    LOADX_FRAGS(0);
    float creg = 0.f;

    // ---------------- main loop: ONE grid barrier per step --------------------
    for (int t = 0; t <= kT; ++t) {
        grid_barrier(bar, bid);
        const ushort* sprev = sB + ((size_t)l * 2 + ((t + 1) & 1)) * (kB * kH);
        bf16x8 as[16];
        if (t < kT || blk < 16) {
            #pragma unroll
            for (int ks = 0; ks < 16; ks++)
                as[ks] = *(const bf16x8*)(sprev + (size_t)mrow * kH + ks * 32 + kq * 8);
        }

        if (t < kT) {
            f32x4 c0 = {bias, bias, bias, bias};
            f32x4 c1 = {0.f, 0.f, 0.f, 0.f};
            f32x4 c2 = {0.f, 0.f, 0.f, 0.f};
            #pragma unroll
            for (int ks = 0; ks < 8; ks++) {          // 3 independent chains for ILP
                c0 = __builtin_amdgcn_mfma_f32_16x16x32_bf16(axp[ks], bxh[ks],     c0, 0, 0, 0);
                c1 = __builtin_amdgcn_mfma_f32_16x16x32_bf16(as[ks],  bsh[ks],     c1, 0, 0, 0);
                c2 = __builtin_amdgcn_mfma_f32_16x16x32_bf16(as[8+ks], bsh[8+ks],  c2, 0, 0, 0);
            }
            #pragma unroll
            for (int r = 0; r < 4; r++)
                lgs[n][wv * 16 + kq * 4 + r] = c0[r] + c1[r] + c2[r];
            __syncthreads();
            const float gi = sigm(lgs[cjj][crow]);
            const float gf = sigm(lgs[4 + cjj][crow]);
            const float gg = tanhf(lgs[8 + cjj][crow]);
            const float go = sigm(lgs[12 + cjj][crow]);
            creg = gf * creg + gi * gg;
            const float sv = go * tanhf(creg);
            ssl[crow * 4 + cjj] = f2bf(sv);
            __syncthreads();
            if (tid < 64) {
                ushort* scur = sB + ((size_t)l * 2 + (t & 1)) * (kB * kH);
                *(uint2*)(scur + (size_t)tid * kH + blk * 4) = *(const uint2*)(ssl + tid * 4);
            }
        }

        if (t >= 1 && blk < 16) {                     // projection, one step behind
            f32x4 p0 = {0.f, 0.f, 0.f, 0.f};
            f32x4 p1 = {0.f, 0.f, 0.f, 0.f};
            #pragma unroll
            for (int ks = 0; ks < 8; ks++) {
                int a0 = ((((n * 16 + ks) * 4 + kq) * 16)) ^ ((n & 7) << 4);
                int a1 = ((((n * 16 + 8 + ks) * 4 + kq) * 16)) ^ ((n & 7) << 4);
                bf16x8 w0 = *(const bf16x8*)((const char*)bpL + a0);
                bf16x8 w1 = *(const bf16x8*)((const char*)bpL + a1);
                p0 = __builtin_amdgcn_mfma_f32_16x16x32_bf16(as[ks],     w0, p0, 0, 0, 0);
                p1 = __builtin_amdgcn_mfma_f32_16x16x32_bf16(as[8 + ks], w1, p1, 0, 0, 0);
            }
            const int pcol = blk * 16 + n;
            #pragma unroll
            for (int r = 0; r < 4; r++)
                outp[((size_t)(wv * 16 + kq * 4 + r) * kT + (t - 1)) * kD + pcol] = p0[r] + p1[r];
        }

        if (t + 1 < kT) LOADX_FRAGS(t + 1);
    }
}

extern "C" void kernel_launch(void* const* d_in, const int* in_sizes, int n_in,
                              void* d_out, int out_size, void* d_ws, size_t ws_size,
                              hipStream_t stream) {
    const float* x1   = (const float*)d_in[0];
    const float* x2   = (const float*)d_in[1];
    const float* wih1 = (const float*)d_in[2];
    const float* whh1 = (const float*)d_in[3];
    const float* b1   = (const float*)d_in[4];
    const float* whr1 = (const float*)d_in[5];
    const float* wih2 = (const float*)d_in[6];
    const float* whh2 = (const float*)d_in[7];
    const float* b2   = (const float*)d_in[8];
    const float* whr2 = (const float*)d_in[9];
    float* outp = (float*)d_out;
    ushort* ws  = (ushort*)d_ws;

    bar_init_kernel<<<1, 64, 0, stream>>>((unsigned*)ws);
    lstm2_kernel<<<dim3(kNB), dim3(kNT), 0, stream>>>(
        x1, x2, wih1, whh1, b1, whr1, wih2, whh2, b2, whr2, outp, ws);
}

// Round 4
// 3805.300 us; speedup vs baseline: 5.8659x; 5.8659x over previous
//
#include <hip/hip_runtime.h>

// R4: kill cache-wide coherence ops. R3's 43.5us/step was fence-dominated
// (__threadfence + acquire-spin => buffer_wbl2/buffer_inv per poll => L2
// wiped every step => 900MB HBM refetch @40GB/s). Now: all cross-block data
// uses per-access device-coherent atomics (relaxed, agent scope => sc0 sc1,
// no cache-wide ops); ordering via s_waitcnt vmcnt(0) before flag RMW.
// Decomposition: per LSTM, 4 batch-teams x 32 hidden-blocks. Block owns
// batch rows [bt*16,+16) x hidden cols [bh*16,+16): cell state in regs,
// team-local 32-block barrier (monotonic counter, padded line). Weights in
// regs (Wih, Wc=Whh@Whr folded) / LDS (Whr). One barrier per step.
constexpr int kB = 64, kT = 512, kD = 256, kH = 512, kG = 2048;
constexpr int kNB = 256, kNT = 256;

typedef __attribute__((ext_vector_type(8))) short bf16x8;
typedef __attribute__((ext_vector_type(4))) float f32x4;
union U4 { unsigned u[4]; bf16x8 v; };

__device__ __forceinline__ ushort f2bf(float x) {
    union { float f; unsigned u; } v; v.f = x;
    unsigned r = v.u + 0x7FFFu + ((v.u >> 16) & 1u);
    return (ushort)(r >> 16);
}
__device__ __forceinline__ unsigned pk2(float a, float b) {
    return (unsigned)f2bf(a) | ((unsigned)f2bf(b) << 16);
}
__device__ __forceinline__ float sigm(float x) { return 1.f / (1.f + __expf(-x)); }

#define AT_LOAD(p)    __hip_atomic_load((p), __ATOMIC_RELAXED, __HIP_MEMORY_SCOPE_AGENT)
#define AT_STORE(p,v) __hip_atomic_store((p), (v), __ATOMIC_RELAXED, __HIP_MEMORY_SCOPE_AGENT)
#define AT_ADD(p,v)   __hip_atomic_fetch_add((p), (v), __ATOMIC_RELAXED, __HIP_MEMORY_SCOPE_AGENT)
#define VMCNT0() asm volatile("s_waitcnt vmcnt(0)" ::: "memory")

__global__ void bar_init_kernel(unsigned* bar) {
    #pragma unroll
    for (int i = 0; i < 4; i++) bar[threadIdx.x * 4 + i] = 0u;  // 1024 uints
}

__global__ void __launch_bounds__(kNT, 1) lstm2_kernel(
    const float* __restrict__ x1, const float* __restrict__ x2,
    const float* __restrict__ wih1, const float* __restrict__ whh1,
    const float* __restrict__ b1,   const float* __restrict__ whr1,
    const float* __restrict__ wih2, const float* __restrict__ whh2,
    const float* __restrict__ b2,   const float* __restrict__ whr2,
    float* __restrict__ out, unsigned* __restrict__ ws)
{
    const int bid = blockIdx.x, tid = threadIdx.x;
    const int l = bid >> 7, b7 = bid & 127;
    const int bteam = b7 >> 5, blkh = b7 & 31;
    const int h0 = blkh * 16, grow0 = bteam * 16;

    const float* x   = l ? x2 : x1;
    const float* wih = l ? wih2 : wih1;
    const float* whh = l ? whh2 : whh1;
    const float* bb  = l ? b2 : b1;
    const float* whr = l ? whr2 : whr1;
    float* outp = out + (l ? (size_t)0 : (size_t)kB * kT * kD);

    unsigned* bar  = ws;                                   // 4KB flags
    unsigned* wc32 = ws + 1024;                            // 2 x [2048][512] bf16 (dword view)
    unsigned* sb32 = wc32 + (size_t)2 * kG * (kH / 2);     // 2 lstm x 2 parity x [64][512] bf16

    __shared__ __align__(16) ushort sbuf[2][16 * 520];     // s(t-1) tile, padded rows
    __shared__ __align__(16) ushort pwl[16 * 520];         // Whr slice (proj blocks)
    __shared__ float lgs[4][16][17];
    __shared__ ushort ssl[256];

    // ---------- P0: Wc = Whh @ Whr (f32 accum -> bf16, sc1 stores) ----------
    {
        const int j  = b7 * 16 + (tid >> 4);               // gate col 0..2047
        const int k0 = (tid & 15) * 32;
        const float* whh_r = whh + (size_t)j * kD;
        float acc[32];
        #pragma unroll
        for (int i = 0; i < 32; i++) acc[i] = 0.f;
        for (int p = 0; p < kD; p++) {
            float w = whh_r[p];
            const float4* wr = (const float4*)(whr + (size_t)p * kH + k0);
            #pragma unroll
            for (int q = 0; q < 8; q++) {
                float4 v = wr[q];
                acc[q*4+0] = fmaf(w, v.x, acc[q*4+0]);
                acc[q*4+1] = fmaf(w, v.y, acc[q*4+1]);
                acc[q*4+2] = fmaf(w, v.z, acc[q*4+2]);
                acc[q*4+3] = fmaf(w, v.w, acc[q*4+3]);
            }
        }
        unsigned* dst = wc32 + (size_t)l * (kG * kH / 2) + (size_t)j * (kH / 2) + k0 / 2;
        #pragma unroll
        for (int i = 0; i < 16; i++) AT_STORE(dst + i, pk2(acc[2*i], acc[2*i+1]));
    }
    AT_STORE(sb32 + bid * 256 + tid, 0u);                  // zero s buffers (both parities)
    VMCNT0();
    __syncthreads();                                       // all waves' vmcnt(0) done
    if (tid == 0) {                                        // one-time global barrier
        unsigned a = AT_ADD(bar + 0, 1u);
        if (a == (unsigned)(kNB - 1)) AT_STORE(bar + 64, 1u);
        while (AT_LOAD(bar + 64) == 0u) __builtin_amdgcn_s_sleep(2);
    }
    __syncthreads();

    // ---------- persistent fragments ----------------------------------------
    const int wv = tid >> 6, lane = tid & 63;
    const int n = lane & 15, kq = lane >> 4;
    const int gcol = wv * kH + h0 + n;                     // wave wv = gate wv
    const float bias = bb[gcol];
    const int mrow = grow0 + n;
    const int crow = tid >> 4, ccol = tid & 15;

    bf16x8 bxh[8];                                         // Wih frags (K=256)
    #pragma unroll
    for (int ks = 0; ks < 8; ks++) {
        const float4* p = (const float4*)(wih + (size_t)gcol * kD + ks * 32 + kq * 8);
        float4 a0 = p[0], a1 = p[1];
        U4 h;
        h.u[0] = pk2(a0.x, a0.y); h.u[1] = pk2(a0.z, a0.w);
        h.u[2] = pk2(a1.x, a1.y); h.u[3] = pk2(a1.z, a1.w);
        bxh[ks] = h.v;
    }
    bf16x8 bsh[16];                                        // Wc frags (K=512), sc1 loads
    {
        const unsigned* wcp = wc32 + (size_t)l * (kG * kH / 2) + (size_t)gcol * (kH / 2);
        #pragma unroll
        for (int ks = 0; ks < 16; ks++) {
            U4 u;
            #pragma unroll
            for (int i = 0; i < 4; i++) u.u[i] = AT_LOAD(wcp + (ks * 32 + kq * 8) / 2 + i);
            bsh[ks] = u.v;
        }
    }
    const bool isProj = (blkh < 16);
    if (isProj) {                                          // Whr slice -> LDS
        const int col = tid >> 4, k0 = (tid & 15) * 32;
        const float4* src = (const float4*)(whr + (size_t)(blkh * 16 + col) * kH + k0);
        ushort* d = pwl + col * 520 + k0;
        #pragma unroll
        for (int i = 0; i < 8; i++) {
            float4 v = src[i];
            d[i*4+0] = f2bf(v.x); d[i*4+1] = f2bf(v.y);
            d[i*4+2] = f2bf(v.z); d[i*4+3] = f2bf(v.w);
        }
    }

    bf16x8 ax[8];                                          // x frags for current t
    #pragma unroll
    for (int ks = 0; ks < 8; ks++) {
        const float4* xp = (const float4*)(x + ((size_t)mrow * kT + 0) * kD + ks * 32 + kq * 8);
        float4 a0 = xp[0], a1 = xp[1];
        U4 f;
        f.u[0] = pk2(a0.x, a0.y); f.u[1] = pk2(a0.z, a0.w);
        f.u[2] = pk2(a1.x, a1.y); f.u[3] = pk2(a1.z, a1.w);
        ax[ks] = f.v;
    }
    float creg = 0.f;

    unsigned* tctr = bar + 128 + (l * 4 + bteam) * 64;     // team barrier (padded line)
    unsigned* tgen = tctr + 32;

    // ---------- main loop: one team barrier per step -------------------------
    for (int t = 0; t <= kT; ++t) {
        if (t == kT && !isProj) break;
        if (tid == 0) {
            while ((int)AT_LOAD(tgen) < t) __builtin_amdgcn_s_sleep(2);
        }
        __syncthreads();
        {   // stage s(t-1) [16 rows][512] -> LDS (sc1 loads, 16 dwords/thread)
            const unsigned* sp = sb32 + (size_t)(l * 2 + ((t + 1) & 1)) * 16384;
            unsigned* sd = (unsigned*)sbuf[t & 1];
            #pragma unroll
            for (int i = 0; i < 16; i++) {
                int d = tid + 256 * i;
                int row = d >> 8, dc = d & 255;
                sd[row * 260 + dc] = AT_LOAD(sp + (grow0 + row) * 256 + dc);
            }
        }
        __syncthreads();
        bf16x8 as[16];
        #pragma unroll
        for (int ks = 0; ks < 16; ks++)
            as[ks] = *(const bf16x8*)(&sbuf[t & 1][n * 520 + ks * 32 + kq * 8]);

        if (t < kT) {
            f32x4 c0 = {bias, bias, bias, bias};
            f32x4 c1 = {0.f, 0.f, 0.f, 0.f};
            f32x4 c2 = {0.f, 0.f, 0.f, 0.f};
            #pragma unroll
            for (int ks = 0; ks < 8; ks++) {
                c0 = __builtin_amdgcn_mfma_f32_16x16x32_bf16(ax[ks],     bxh[ks],    c0, 0, 0, 0);
                c1 = __builtin_amdgcn_mfma_f32_16x16x32_bf16(as[ks],     bsh[ks],    c1, 0, 0, 0);
                c2 = __builtin_amdgcn_mfma_f32_16x16x32_bf16(as[8+ks],   bsh[8+ks],  c2, 0, 0, 0);
            }
            #pragma unroll
            for (int r = 0; r < 4; r++)
                lgs[wv][kq * 4 + r][n] = c0[r] + c1[r] + c2[r];
            __syncthreads();
            const float gi = sigm(lgs[0][crow][ccol]);
            const float gf = sigm(lgs[1][crow][ccol]);
            const float gg = tanhf(lgs[2][crow][ccol]);
            const float go = sigm(lgs[3][crow][ccol]);
            creg = gf * creg + gi * gg;
            const float sv = go * tanhf(creg);
            ssl[crow * 16 + ccol] = f2bf(sv);
            __syncthreads();
            if (tid < 64) {                                // wave 0: publish s(t) slice
                unsigned* sc = sb32 + (size_t)(l * 2 + (t & 1)) * 16384;
                const unsigned* sl = (const unsigned*)ssl;
                int r0 = tid >> 3, cp = tid & 7;
                AT_STORE(sc + (grow0 + r0) * 256 + blkh * 8 + cp,     sl[r0 * 8 + cp]);
                AT_STORE(sc + (grow0 + r0 + 8) * 256 + blkh * 8 + cp, sl[(r0 + 8) * 8 + cp]);
                VMCNT0();
            }
            if (tid == 0) {                                // arrive
                unsigned a = AT_ADD(tctr, 1u);
                if (a == (unsigned)(32 * (t + 1) - 1)) AT_STORE(tgen, (unsigned)(t + 1));
            }
        }

        if (t >= 1 && isProj && tid < 64) {                // out(t-1) = s(t-1).Whr^T
            f32x4 p0 = {0.f, 0.f, 0.f, 0.f};
            f32x4 p1 = {0.f, 0.f, 0.f, 0.f};
            #pragma unroll
            for (int ks = 0; ks < 8; ks++) {
                bf16x8 w0 = *(const bf16x8*)(&pwl[n * 520 + ks * 32 + kq * 8]);
                bf16x8 w1 = *(const bf16x8*)(&pwl[n * 520 + (8 + ks) * 32 + kq * 8]);
                p0 = __builtin_amdgcn_mfma_f32_16x16x32_bf16(as[ks],     w0, p0, 0, 0, 0);
                p1 = __builtin_amdgcn_mfma_f32_16x16x32_bf16(as[8 + ks], w1, p1, 0, 0, 0);
            }
            #pragma unroll
            for (int r = 0; r < 4; r++)
                outp[((size_t)(grow0 + kq * 4 + r) * kT + (t - 1)) * kD + blkh * 16 + n] = p0[r] + p1[r];
        }

        if (t + 1 < kT) {                                  // prefetch x(t+1) in poll shadow
            #pragma unroll
            for (int ks = 0; ks < 8; ks++) {
                const float4* xp = (const float4*)(x + ((size_t)mrow * kT + (t + 1)) * kD + ks * 32 + kq * 8);
                float4 a0 = xp[0], a1 = xp[1];
                U4 f;
                f.u[0] = pk2(a0.x, a0.y); f.u[1] = pk2(a0.z, a0.w);
                f.u[2] = pk2(a1.x, a1.y); f.u[3] = pk2(a1.z, a1.w);
                ax[ks] = f.v;
            }
        }
    }
}

extern "C" void kernel_launch(void* const* d_in, const int* in_sizes, int n_in,
                              void* d_out, int out_size, void* d_ws, size_t ws_size,
                              hipStream_t stream) {
    const float* x1   = (const float*)d_in[0];
    const float* x2   = (const float*)d_in[1];
    const float* wih1 = (const float*)d_in[2];
    const float* whh1 = (const float*)d_in[3];
    const float* b1   = (const float*)d_in[4];
    const float* whr1 = (const float*)d_in[5];
    const float* wih2 = (const float*)d_in[6];
    const float* whh2 = (const float*)d_in[7];
    const float* b2   = (const float*)d_in[8];
    const float* whr2 = (const float*)d_in[9];
    float* outp  = (float*)d_out;
    unsigned* ws = (unsigned*)d_ws;

    bar_init_kernel<<<1, 256, 0, stream>>>(ws);
    lstm2_kernel<<<dim3(kNB), dim3(kNT), 0, stream>>>(
        x1, x2, wih1, whh1, b1, whr1, wih2, whh2, b2, whr2, outp, ws);
}